// Round 6
// baseline (233.500 us; speedup 1.0000x reference)
//
#include <hip/hip_runtime.h>

typedef _Float16 half_t;
typedef __attribute__((ext_vector_type(8))) _Float16 half8;
typedef __attribute__((ext_vector_type(2))) __fp16 fp16x2;
typedef __attribute__((ext_vector_type(4))) float f32x4;
typedef __attribute__((ext_vector_type(16))) float f32x16;

#define EMB 768
#define HEADS 8
#define HD 96
#define BB 4
#define NN 2048
#define BN (BB*NN)   // 8192

static __device__ __forceinline__ f32x4 mfma16(half8 a, half8 b, f32x4 c) {
    return __builtin_amdgcn_mfma_f32_16x16x32_f16(a, b, c, 0, 0, 0);
}
static __device__ __forceinline__ f32x16 mfma32(half8 a, half8 b, f32x16 c) {
    return __builtin_amdgcn_mfma_f32_32x32x16_f16(a, b, c, 0, 0, 0);
}
static __device__ __forceinline__ unsigned pkrtz(float a, float b) {
    fp16x2 h = __builtin_amdgcn_cvt_pkrtz(a, b);
    return __builtin_bit_cast(unsigned, h);
}
static __device__ __forceinline__ unsigned sx32(unsigned v) {
    return (unsigned)__shfl_xor((int)v, 32);
}
static __device__ __forceinline__ half8 pack8(float4 a, float4 b) {
    union { unsigned u[4]; half8 h; } t;
    t.u[0] = pkrtz(a.x, a.y); t.u[1] = pkrtz(a.z, a.w);
    t.u[2] = pkrtz(b.x, b.y); t.u[3] = pkrtz(b.z, b.w);
    return t.h;
}

// ---------------------------------------------------------------------------
// W[768][768] fp32 -> WT[768][768] f16 (transposed). grid (24,24,4), block 256.
// ---------------------------------------------------------------------------
__global__ __launch_bounds__(256) void cvt_transpose_w(
    const float* __restrict__ W0, const float* __restrict__ W1,
    const float* __restrict__ W2, const float* __restrict__ W3,
    half_t* __restrict__ T0, half_t* __restrict__ T1,
    half_t* __restrict__ T2, half_t* __restrict__ T3)
{
    const float* W; half_t* T;
    switch (blockIdx.z) {
        case 0: W = W0; T = T0; break;
        case 1: W = W1; T = T1; break;
        case 2: W = W2; T = T2; break;
        default: W = W3; T = T3; break;
    }
    __shared__ float ls[32][33];
    const int k0 = blockIdx.x * 32, n0 = blockIdx.y * 32;
    const int r = threadIdx.x >> 3, c4 = (threadIdx.x & 7) * 4;
    float4 v = *(const float4*)&W[(size_t)(k0 + r) * EMB + n0 + c4];
    ls[r][c4+0] = v.x; ls[r][c4+1] = v.y; ls[r][c4+2] = v.z; ls[r][c4+3] = v.w;
    __syncthreads();
    union { half_t h[4]; uint2 u; } t;
    #pragma unroll
    for (int j = 0; j < 4; ++j) t.h[j] = (half_t)ls[c4 + j][r];
    *(uint2*)&T[(size_t)(n0 + r) * EMB + k0 + c4] = t.u;
}

// ---------------------------------------------------------------------------
// QKV projection, f16 MFMA, A-operand converted f32->f16 during staging.
// 128x128 tile, BK=32, 4 waves. Q (scaled by log2e), K written [bh][n][96];
// V written transposed [bh][96][n]. grid (64, 6, 3), block 256.
// ---------------------------------------------------------------------------
__global__ __launch_bounds__(256) void proj_qkv_h(
    const float* __restrict__ x,
    const half_t* __restrict__ WqT, const float* __restrict__ bq,
    const half_t* __restrict__ WkT, const float* __restrict__ bk,
    const half_t* __restrict__ WvT, const float* __restrict__ bv,
    half_t* __restrict__ Qo, half_t* __restrict__ Ko, half_t* __restrict__ Vt)
{
    const half_t* WT; const float* bias;
    const int z = blockIdx.z;
    if (z == 0)      { WT = WqT; bias = bq; }
    else if (z == 1) { WT = WkT; bias = bk; }
    else             { WT = WvT; bias = bv; }

    __shared__ half_t As[128][56];
    __shared__ half_t Bs[128][56];

    const int tid = threadIdx.x;
    const int lane = tid & 63;
    const int wid = tid >> 6;
    const int lr = lane & 15;
    const int lkg = lane >> 4;
    const int wm = (wid >> 1) * 64;
    const int wn = (wid & 1) * 64;
    const int mbase = blockIdx.x * 128;
    const int nbase = blockIdx.y * 128;

    const int srr = tid >> 2;
    const int skk = (tid & 3) * 8;

    f32x4 acc[4][4];
    const f32x4 z4 = {0.f, 0.f, 0.f, 0.f};
    #pragma unroll
    for (int i = 0; i < 4; ++i)
        #pragma unroll
        for (int j = 0; j < 4; ++j) acc[i][j] = z4;

    const float*  aptr = x  + (size_t)(mbase + srr) * EMB + skk;
    const half_t* bptr = WT + (size_t)(nbase + srr) * EMB + skk;

    half8 a0 = pack8(*(const float4*)(aptr),
                     *(const float4*)(aptr + 4));
    half8 a1 = pack8(*(const float4*)(aptr + 64 * EMB),
                     *(const float4*)(aptr + 64 * EMB + 4));
    half8 b0 = *(const half8*)bptr;
    half8 b1 = *(const half8*)(bptr + 64 * EMB);

    for (int k0 = 0; k0 < EMB; k0 += 32) {
        __syncthreads();
        *(half8*)&As[srr][skk]      = a0;
        *(half8*)&As[srr + 64][skk] = a1;
        *(half8*)&Bs[srr][skk]      = b0;
        *(half8*)&Bs[srr + 64][skk] = b1;
        __syncthreads();
        if (k0 + 32 < EMB) {
            a0 = pack8(*(const float4*)(aptr + k0 + 32),
                       *(const float4*)(aptr + k0 + 36));
            a1 = pack8(*(const float4*)(aptr + k0 + 32 + 64 * EMB),
                       *(const float4*)(aptr + k0 + 36 + 64 * EMB));
            b0 = *(const half8*)(bptr + k0 + 32);
            b1 = *(const half8*)(bptr + k0 + 32 + 64 * EMB);
        }
        half8 af[4], bf[4];
        #pragma unroll
        for (int mi = 0; mi < 4; ++mi)
            af[mi] = *(const half8*)&As[wm + mi*16 + lr][lkg*8];
        #pragma unroll
        for (int ni = 0; ni < 4; ++ni)
            bf[ni] = *(const half8*)&Bs[wn + ni*16 + lr][lkg*8];
        #pragma unroll
        for (int mi = 0; mi < 4; ++mi)
            #pragma unroll
            for (int ni = 0; ni < 4; ++ni)
                acc[mi][ni] = mfma16(af[mi], bf[ni], acc[mi][ni]);
    }

    // Q pre-scaled by log2(e): softmax via exp2
    const float qscale = (z == 0) ? 1.4426950408889634f : 1.0f;

    #pragma unroll
    for (int ni = 0; ni < 4; ++ni) {
        const int e = nbase + wn + ni*16 + lr;
        const float be = bias[e];
        const int h = e / HD, d = e % HD;
        #pragma unroll
        for (int mi = 0; mi < 4; ++mi) {
            const int row0 = mbase + wm + mi*16 + lkg*4;
            const int b = row0 >> 11, n0 = row0 & (NN - 1);
            if (z == 2) {
                union { half_t hh[4]; uint2 u; } t;
                #pragma unroll
                for (int r = 0; r < 4; ++r) t.hh[r] = (half_t)(acc[mi][ni][r] + be);
                *(uint2*)&Vt[((size_t)(b*HEADS + h) * HD + d) * NN + n0] = t.u;
            } else {
                half_t* outp = (z == 0) ? Qo : Ko;
                #pragma unroll
                for (int r = 0; r < 4; ++r)
                    outp[((size_t)(b*HEADS + h) * NN + n0 + r) * HD + d] =
                        (half_t)((acc[mi][ni][r] + be) * qscale);
            }
        }
    }
}

// ---------------------------------------------------------------------------
// Flash attention v3: QBLK=64, intra-block kv-split.
// 4 waves: qsub = wid&1 (q rows), kvhalf = wid>>1 (kv rows of each tile).
// Wave pairs (0,2)/(1,3) merge (m,l,O) through LDS at the end.
// grid (32, 32), block 256.
// ---------------------------------------------------------------------------
__global__ __launch_bounds__(256, 4) void attn_h(
    const half_t* __restrict__ Qh, const half_t* __restrict__ Kh,
    const half_t* __restrict__ Vth, half_t* __restrict__ AOh)
{
    __shared__ __align__(16) char smem[25088];
    // Q stage [64][192B] = 12288; K [64][192B] at 0 = 12288, V [96][128B] at
    // 12288 = 12288; combine xfer 128 records x 49 f32 = 25088.

    const int tid = threadIdx.x;
    const int lane = tid & 63;
    const int wid = tid >> 6;
    const int l31 = lane & 31;
    const int b5 = lane >> 5;
    const int qsub = wid & 1;
    const int sub = wid >> 1;          // kv half of each staged tile
    const int qbase = blockIdx.x * 64;
    const int bh = blockIdx.y;

    const half_t* Qp = Qh + (size_t)bh * NN * HD;
    const half_t* Kp = Kh + (size_t)bh * NN * HD;
    const half_t* Vp = Vth + (size_t)bh * HD * NN;
    half_t* AOp = AOh + (size_t)bh * NN * HD;

    // ---- preload K/V tile 0 into regs ----
    const int kr = tid >> 2;               // K row 0..63
    const int kcb = (tid & 3) * 48;        // K col byte
    const int vd = tid >> 1;               // V row 0..95 (tid<192)
    const int vcb = (tid & 1) * 64;        // V col byte
    half8 kv0, kv1, kv2, vv0, vv1, vv2, vv3;
    {
        const half_t* ksrc = Kp + (size_t)kr * HD + kcb / 2;
        kv0 = *(const half8*)(ksrc);
        kv1 = *(const half8*)(ksrc + 8);
        kv2 = *(const half8*)(ksrc + 16);
        if (tid < 192) {
            const half_t* vsrc = Vp + (size_t)vd * NN + vcb / 2;
            vv0 = *(const half8*)(vsrc);      vv1 = *(const half8*)(vsrc + 8);
            vv2 = *(const half8*)(vsrc + 16); vv3 = *(const half8*)(vsrc + 24);
        }
    }

    // ---- stage Q [64][96] swizzled, read frags, release LDS ----
    {
        const int r = tid >> 2;
        const int cb = (tid & 3) * 48;
        const half_t* src = Qp + (size_t)(qbase + r) * HD + cb / 2;
        #pragma unroll
        for (int c = 0; c < 3; ++c) {
            half8 q = *(const half8*)(src + c * 8);
            *(half8*)(smem + ((r * 192 + cb + c * 16) ^ ((r & 7) << 4))) = q;
        }
    }
    __syncthreads();
    half8 qf[6];
    {
        const int r = qsub * 32 + l31;
        #pragma unroll
        for (int kg = 0; kg < 6; ++kg)
            qf[kg] = *(const half8*)(smem + ((r * 192 + kg * 32 + 16 * b5) ^ ((r & 7) << 4)));
    }
    __syncthreads();

    // ---- state ----
    f32x16 acc[3];
    const f32x16 z16 = {0.f,0.f,0.f,0.f,0.f,0.f,0.f,0.f,0.f,0.f,0.f,0.f,0.f,0.f,0.f,0.f};
    acc[0] = z16; acc[1] = z16; acc[2] = z16;
    float mreg = -1e30f, lreg = 0.f;

    const int kvrow = sub * 32 + l31;      // this wave's kv row within a tile

    for (int kt = 0; kt < NN / 64; ++kt) {
        // write staged K/V tile (swizzled)
        *(half8*)(smem + ((kr * 192 + kcb +  0) ^ ((kr & 7) << 4))) = kv0;
        *(half8*)(smem + ((kr * 192 + kcb + 16) ^ ((kr & 7) << 4))) = kv1;
        *(half8*)(smem + ((kr * 192 + kcb + 32) ^ ((kr & 7) << 4))) = kv2;
        if (tid < 192) {
            char* vb = smem + 12288;
            *(half8*)(vb + ((vd * 128 + vcb +  0) ^ ((vd & 7) << 4))) = vv0;
            *(half8*)(vb + ((vd * 128 + vcb + 16) ^ ((vd & 7) << 4))) = vv1;
            *(half8*)(vb + ((vd * 128 + vcb + 32) ^ ((vd & 7) << 4))) = vv2;
            *(half8*)(vb + ((vd * 128 + vcb + 48) ^ ((vd & 7) << 4))) = vv3;
        }
        __syncthreads();

        // prefetch next tile
        if (kt + 1 < NN / 64) {
            const int kb = (kt + 1) * 64;
            const half_t* ksrc = Kp + (size_t)(kb + kr) * HD + kcb / 2;
            kv0 = *(const half8*)(ksrc);
            kv1 = *(const half8*)(ksrc + 8);
            kv2 = *(const half8*)(ksrc + 16);
            if (tid < 192) {
                const half_t* vsrc = Vp + (size_t)vd * NN + kb + vcb / 2;
                vv0 = *(const half8*)(vsrc);      vv1 = *(const half8*)(vsrc + 8);
                vv2 = *(const half8*)(vsrc + 16); vv3 = *(const half8*)(vsrc + 24);
            }
        }

        // S^T[kv][q] over this wave's 32-kv subtile
        f32x16 st = z16;
        #pragma unroll
        for (int kg = 0; kg < 6; ++kg) {
            half8 kf = *(const half8*)(smem +
                ((kvrow * 192 + kg * 32 + 16 * b5) ^ ((kvrow & 7) << 4)));
            st = mfma32(kf, qf[kg], st);
        }

        // row max over lane's 16 kv + partner's 16
        float tm = st[0];
        #pragma unroll
        for (int i = 1; i < 16; ++i) tm = fmaxf(tm, st[i]);
        tm = fmaxf(tm, __shfl_xor(tm, 32));

        // defer-max
        if (!__all(tm <= mreg + 8.0f)) {
            const float mn = fmaxf(mreg, tm);
            const float sc = exp2f(mreg - mn);
            lreg *= sc;
            #pragma unroll
            for (int db = 0; db < 3; ++db)
                #pragma unroll
                for (int i = 0; i < 16; ++i) acc[db][i] *= sc;
            mreg = mn;
        }

        // P = exp2(S^T - m), row sum
        float rs = 0.f;
        #pragma unroll
        for (int i = 0; i < 16; ++i) {
            const float p = exp2f(st[i] - mreg);
            st[i] = p;
            rs += p;
        }
        rs += __shfl_xor(rs, 32);
        lreg += rs;

        // pack P to f16
        unsigned pk[4][2];
        #pragma unroll
        for (int rr = 0; rr < 4; ++rr) {
            pk[rr][0] = pkrtz(st[rr*4+0], st[rr*4+1]);
            pk[rr][1] = pkrtz(st[rr*4+2], st[rr*4+3]);
        }

        // P^T B-frags via b5-partner exchange; O^T accumulate
        #pragma unroll
        for (int ks = 0; ks < 2; ++ks) {
            const unsigned z0 = b5 ? pk[2*ks][0] : pk[2*ks+1][0];
            const unsigned z1 = b5 ? pk[2*ks][1] : pk[2*ks+1][1];
            const unsigned x0 = sx32(z0);
            const unsigned x1 = sx32(z1);
            union { unsigned u[4]; half8 h; } afu;
            afu.u[0] = b5 ? x0 : pk[2*ks][0];
            afu.u[1] = b5 ? x1 : pk[2*ks][1];
            afu.u[2] = b5 ? pk[2*ks+1][0] : x0;
            afu.u[3] = b5 ? pk[2*ks+1][1] : x1;
            const half8 af = afu.h;
            #pragma unroll
            for (int db = 0; db < 3; ++db) {
                const int d = db * 32 + l31;
                half8 vf = *(const half8*)(smem + 12288 +
                    ((d * 128 + sub * 64 + ks * 32 + 16 * b5) ^ ((d & 7) << 4)));
                acc[db] = mfma32(vf, af, acc[db]);
            }
        }
        __syncthreads();
    }

    // ---- combine wave pairs (0,2) and (1,3) ----
    float* fb = (float*)smem;
    fb[tid] = mreg;
    fb[256 + tid] = lreg;
    __syncthreads();
    const float mp = fb[tid ^ 128];
    const float lp = fb[256 + (tid ^ 128)];
    const float mc = fmaxf(mreg, mp);
    const float sc = exp2f(mreg - mc);
    const float lc = lreg * sc + lp * exp2f(mp - mc);
    __syncthreads();
    if (wid >= 2) {
        float* rec = fb + (qsub * 64 + lane) * 49;
        #pragma unroll
        for (int db = 0; db < 3; ++db)
            #pragma unroll
            for (int i = 0; i < 16; ++i) rec[db*16 + i] = acc[db][i] * sc;
    }
    __syncthreads();
    if (wid < 2) {
        const float* rec = fb + (qsub * 64 + lane) * 49;
        const float isq = 0.10206207261596577f;   // 1/sqrt(96), post-softmax per ref
        const float inv = isq / lc;
        const int q = qbase + qsub * 32 + l31;
        half_t* dst = AOp + (size_t)q * HD;
        #pragma unroll
        for (int db = 0; db < 3; ++db)
            #pragma unroll
            for (int rr = 0; rr < 4; ++rr) {
                const int d0 = db * 32 + rr * 8 + 4 * b5;
                union { half_t h[4]; uint2 u; } t;
                #pragma unroll
                for (int r = 0; r < 4; ++r)
                    t.h[r] = (half_t)((acc[db][rr*4 + r] * sc + rec[db*16 + rr*4 + r]) * inv);
                *(uint2*)&dst[d0] = t.u;
            }
    }
}

// ---------------------------------------------------------------------------
// Output projection: out(fp32) = AO(head-split f16) @ WoT + bo.
// ---------------------------------------------------------------------------
__global__ __launch_bounds__(256) void proj_out_h(
    const half_t* __restrict__ AOh, const half_t* __restrict__ WoT,
    const float* __restrict__ bo, float* __restrict__ out)
{
    __shared__ half_t As[128][56];
    __shared__ half_t Bs[128][56];

    const int tid = threadIdx.x;
    const int lane = tid & 63;
    const int wid = tid >> 6;
    const int lr = lane & 15;
    const int lkg = lane >> 4;
    const int wm = (wid >> 1) * 64;
    const int wn = (wid & 1) * 64;
    const int mbase = blockIdx.x * 128;
    const int nbase = blockIdx.y * 128;

    const int srr = tid >> 2;
    const int skk = (tid & 3) * 8;

    const int arow0 = mbase + srr;
    const int ab0 = arow0 >> 11, an0 = arow0 & (NN - 1);
    const int arow1 = arow0 + 64;
    const int ab1 = arow1 >> 11, an1 = arow1 & (NN - 1);

    f32x4 acc[4][4];
    const f32x4 z4 = {0.f, 0.f, 0.f, 0.f};
    #pragma unroll
    for (int i = 0; i < 4; ++i)
        #pragma unroll
        for (int j = 0; j < 4; ++j) acc[i][j] = z4;

    const half_t* bptr = WoT + (size_t)(nbase + srr) * EMB + skk;

#define ALOAD(b_, n_, k0_) \
    (*(const half8*)&AOh[((size_t)((b_)*HEADS + (k0_)/HD) * NN + (n_)) * HD + ((k0_)%HD) + skk])

    half8 a0 = ALOAD(ab0, an0, 0);
    half8 a1 = ALOAD(ab1, an1, 0);
    half8 b0 = *(const half8*)bptr;
    half8 b1 = *(const half8*)(bptr + 64 * EMB);

    for (int k0 = 0; k0 < EMB; k0 += 32) {
        __syncthreads();
        *(half8*)&As[srr][skk]      = a0;
        *(half8*)&As[srr + 64][skk] = a1;
        *(half8*)&Bs[srr][skk]      = b0;
        *(half8*)&Bs[srr + 64][skk] = b1;
        __syncthreads();
        if (k0 + 32 < EMB) {
            const int kn = k0 + 32;
            a0 = ALOAD(ab0, an0, kn);
            a1 = ALOAD(ab1, an1, kn);
            b0 = *(const half8*)(bptr + kn);
            b1 = *(const half8*)(bptr + kn + 64 * EMB);
        }
        half8 af[4], bf[4];
        #pragma unroll
        for (int mi = 0; mi < 4; ++mi)
            af[mi] = *(const half8*)&As[wm + mi*16 + lr][lkg*8];
        #pragma unroll
        for (int ni = 0; ni < 4; ++ni)
            bf[ni] = *(const half8*)&Bs[wn + ni*16 + lr][lkg*8];
        #pragma unroll
        for (int mi = 0; mi < 4; ++mi)
            #pragma unroll
            for (int ni = 0; ni < 4; ++ni)
                acc[mi][ni] = mfma16(af[mi], bf[ni], acc[mi][ni]);
    }
#undef ALOAD

    #pragma unroll
    for (int ni = 0; ni < 4; ++ni) {
        const int e = nbase + wn + ni*16 + lr;
        const float be = bo[e];
        #pragma unroll
        for (int mi = 0; mi < 4; ++mi) {
            const int row0 = mbase + wm + mi*16 + lkg*4;
            #pragma unroll
            for (int r = 0; r < 4; ++r)
                out[(size_t)(row0 + r) * EMB + e] = acc[mi][ni][r] + be;
        }
    }
}

// ---------------------------------------------------------------------------
extern "C" void kernel_launch(void* const* d_in, const int* in_sizes, int n_in,
                              void* d_out, int out_size, void* d_ws, size_t ws_size,
                              hipStream_t stream)
{
    const float* x  = (const float*)d_in[0];
    const float* Wq = (const float*)d_in[1];
    const float* bq = (const float*)d_in[2];
    const float* Wk = (const float*)d_in[3];
    const float* bk = (const float*)d_in[4];
    const float* Wv = (const float*)d_in[5];
    const float* bv = (const float*)d_in[6];
    const float* Wo = (const float*)d_in[7];
    const float* bo = (const float*)d_in[8];

    const size_t SZ = (size_t)BN * EMB;   // 6,291,456
    const size_t WS = (size_t)EMB * EMB;  //   589,824

    half_t* ws  = (half_t*)d_ws;
    half_t* WqT = ws;
    half_t* WkT = WqT + WS;
    half_t* WvT = WkT + WS;
    half_t* WoT = WvT + WS;
    half_t* Qh  = WoT + WS;
    half_t* Kh  = Qh  + SZ;
    half_t* Vth = Kh  + SZ;
    half_t* AOh = Vth + SZ;

    cvt_transpose_w<<<dim3(EMB/32, EMB/32, 4), 256, 0, stream>>>(
        Wq, Wk, Wv, Wo, WqT, WkT, WvT, WoT);

    proj_qkv_h<<<dim3(BN/128, EMB/128, 3), 256, 0, stream>>>(
        x, WqT, bq, WkT, bk, WvT, bv, Qh, Kh, Vth);

    attn_h<<<dim3(NN/64, BB*HEADS), 256, 0, stream>>>(Qh, Kh, Vth, AOh);

    proj_out_h<<<dim3(BN/128, EMB/128), 256, 0, stream>>>(AOh, WoT, bo, (float*)d_out);
}

// Round 7
// 167.788 us; speedup vs baseline: 1.3916x; 1.3916x over previous
//
#include <hip/hip_runtime.h>

typedef _Float16 half_t;
typedef __attribute__((ext_vector_type(8))) _Float16 half8;
typedef __attribute__((ext_vector_type(2))) __fp16 fp16x2;
typedef __attribute__((ext_vector_type(4))) float f32x4;
typedef __attribute__((ext_vector_type(16))) float f32x16;

#define EMB 768
#define HEADS 8
#define HD 96
#define BB 4
#define NN 2048
#define BN (BB*NN)   // 8192

static __device__ __forceinline__ f32x4 mfma16(half8 a, half8 b, f32x4 c) {
    return __builtin_amdgcn_mfma_f32_16x16x32_f16(a, b, c, 0, 0, 0);
}
static __device__ __forceinline__ f32x16 mfma32(half8 a, half8 b, f32x16 c) {
    return __builtin_amdgcn_mfma_f32_32x32x16_f16(a, b, c, 0, 0, 0);
}
static __device__ __forceinline__ unsigned pkrtz(float a, float b) {
    fp16x2 h = __builtin_amdgcn_cvt_pkrtz(a, b);
    return __builtin_bit_cast(unsigned, h);
}
static __device__ __forceinline__ unsigned sx32(unsigned v) {
    return (unsigned)__shfl_xor((int)v, 32);
}
static __device__ __forceinline__ half8 pack8(float4 a, float4 b) {
    union { unsigned u[4]; half8 h; } t;
    t.u[0] = pkrtz(a.x, a.y); t.u[1] = pkrtz(a.z, a.w);
    t.u[2] = pkrtz(b.x, b.y); t.u[3] = pkrtz(b.z, b.w);
    return t.h;
}

// ---------------------------------------------------------------------------
// W[768][768] fp32 -> WT[768][768] f16 (transposed). grid (24,24,4), block 256.
// ---------------------------------------------------------------------------
__global__ __launch_bounds__(256) void cvt_transpose_w(
    const float* __restrict__ W0, const float* __restrict__ W1,
    const float* __restrict__ W2, const float* __restrict__ W3,
    half_t* __restrict__ T0, half_t* __restrict__ T1,
    half_t* __restrict__ T2, half_t* __restrict__ T3)
{
    const float* W; half_t* T;
    switch (blockIdx.z) {
        case 0: W = W0; T = T0; break;
        case 1: W = W1; T = T1; break;
        case 2: W = W2; T = T2; break;
        default: W = W3; T = T3; break;
    }
    __shared__ float ls[32][33];
    const int k0 = blockIdx.x * 32, n0 = blockIdx.y * 32;
    const int r = threadIdx.x >> 3, c4 = (threadIdx.x & 7) * 4;
    float4 v = *(const float4*)&W[(size_t)(k0 + r) * EMB + n0 + c4];
    ls[r][c4+0] = v.x; ls[r][c4+1] = v.y; ls[r][c4+2] = v.z; ls[r][c4+3] = v.w;
    __syncthreads();
    union { half_t h[4]; uint2 u; } t;
    #pragma unroll
    for (int j = 0; j < 4; ++j) t.h[j] = (half_t)ls[c4 + j][r];
    *(uint2*)&T[(size_t)(n0 + r) * EMB + k0 + c4] = t.u;
}

// ---------------------------------------------------------------------------
// QKV projection, f16 MFMA, A-operand converted f32->f16 during staging.
// 128x128 tile, BK=32, 4 waves. Q (scaled by log2e), K written [bh][n][96];
// V written transposed [bh][96][n]. grid (64, 6, 3), block 256.
// ---------------------------------------------------------------------------
__global__ __launch_bounds__(256) void proj_qkv_h(
    const float* __restrict__ x,
    const half_t* __restrict__ WqT, const float* __restrict__ bq,
    const half_t* __restrict__ WkT, const float* __restrict__ bk,
    const half_t* __restrict__ WvT, const float* __restrict__ bv,
    half_t* __restrict__ Qo, half_t* __restrict__ Ko, half_t* __restrict__ Vt)
{
    const half_t* WT; const float* bias;
    const int z = blockIdx.z;
    if (z == 0)      { WT = WqT; bias = bq; }
    else if (z == 1) { WT = WkT; bias = bk; }
    else             { WT = WvT; bias = bv; }

    __shared__ half_t As[128][56];
    __shared__ half_t Bs[128][56];

    const int tid = threadIdx.x;
    const int lane = tid & 63;
    const int wid = tid >> 6;
    const int lr = lane & 15;
    const int lkg = lane >> 4;
    const int wm = (wid >> 1) * 64;
    const int wn = (wid & 1) * 64;
    const int mbase = blockIdx.x * 128;
    const int nbase = blockIdx.y * 128;

    const int srr = tid >> 2;
    const int skk = (tid & 3) * 8;

    f32x4 acc[4][4];
    const f32x4 z4 = {0.f, 0.f, 0.f, 0.f};
    #pragma unroll
    for (int i = 0; i < 4; ++i)
        #pragma unroll
        for (int j = 0; j < 4; ++j) acc[i][j] = z4;

    const float*  aptr = x  + (size_t)(mbase + srr) * EMB + skk;
    const half_t* bptr = WT + (size_t)(nbase + srr) * EMB + skk;

    half8 a0 = pack8(*(const float4*)(aptr),
                     *(const float4*)(aptr + 4));
    half8 a1 = pack8(*(const float4*)(aptr + 64 * EMB),
                     *(const float4*)(aptr + 64 * EMB + 4));
    half8 b0 = *(const half8*)bptr;
    half8 b1 = *(const half8*)(bptr + 64 * EMB);

    for (int k0 = 0; k0 < EMB; k0 += 32) {
        __syncthreads();
        *(half8*)&As[srr][skk]      = a0;
        *(half8*)&As[srr + 64][skk] = a1;
        *(half8*)&Bs[srr][skk]      = b0;
        *(half8*)&Bs[srr + 64][skk] = b1;
        __syncthreads();
        if (k0 + 32 < EMB) {
            a0 = pack8(*(const float4*)(aptr + k0 + 32),
                       *(const float4*)(aptr + k0 + 36));
            a1 = pack8(*(const float4*)(aptr + k0 + 32 + 64 * EMB),
                       *(const float4*)(aptr + k0 + 36 + 64 * EMB));
            b0 = *(const half8*)(bptr + k0 + 32);
            b1 = *(const half8*)(bptr + k0 + 32 + 64 * EMB);
        }
        half8 af[4], bf[4];
        #pragma unroll
        for (int mi = 0; mi < 4; ++mi)
            af[mi] = *(const half8*)&As[wm + mi*16 + lr][lkg*8];
        #pragma unroll
        for (int ni = 0; ni < 4; ++ni)
            bf[ni] = *(const half8*)&Bs[wn + ni*16 + lr][lkg*8];
        #pragma unroll
        for (int mi = 0; mi < 4; ++mi)
            #pragma unroll
            for (int ni = 0; ni < 4; ++ni)
                acc[mi][ni] = mfma16(af[mi], bf[ni], acc[mi][ni]);
    }

    // Q pre-scaled by log2(e): softmax via exp2
    const float qscale = (z == 0) ? 1.4426950408889634f : 1.0f;

    #pragma unroll
    for (int ni = 0; ni < 4; ++ni) {
        const int e = nbase + wn + ni*16 + lr;
        const float be = bias[e];
        const int h = e / HD, d = e % HD;
        #pragma unroll
        for (int mi = 0; mi < 4; ++mi) {
            const int row0 = mbase + wm + mi*16 + lkg*4;
            const int b = row0 >> 11, n0 = row0 & (NN - 1);
            if (z == 2) {
                union { half_t hh[4]; uint2 u; } t;
                #pragma unroll
                for (int r = 0; r < 4; ++r) t.hh[r] = (half_t)(acc[mi][ni][r] + be);
                *(uint2*)&Vt[((size_t)(b*HEADS + h) * HD + d) * NN + n0] = t.u;
            } else {
                half_t* outp = (z == 0) ? Qo : Ko;
                #pragma unroll
                for (int r = 0; r < 4; ++r)
                    outp[((size_t)(b*HEADS + h) * NN + n0 + r) * HD + d] =
                        (half_t)((acc[mi][ni][r] + be) * qscale);
            }
        }
    }
}

// ---------------------------------------------------------------------------
// Flash attention v3b: QBLK=64, intra-block kv-split, launch_bounds(256,3)
// (v3's (256,4) capped regs at 128 -> accumulator spill -> 354 MB scratch).
// 4 waves: qsub = wid&1 (q rows), kvhalf = wid>>1. Pairs (0,2)/(1,3) merge.
// grid (32, 32), block 256.
// ---------------------------------------------------------------------------
__global__ __launch_bounds__(256, 3) void attn_h(
    const half_t* __restrict__ Qh, const half_t* __restrict__ Kh,
    const half_t* __restrict__ Vth, half_t* __restrict__ AOh)
{
    __shared__ __align__(16) char smem[25088];
    // Q stage [64][192B] = 12288; K [64][192B] at 0, V [96][128B] at 12288;
    // combine xfer 128 records x 49 f32 = 25088.

    const int tid = threadIdx.x;
    const int lane = tid & 63;
    const int wid = tid >> 6;
    const int l31 = lane & 31;
    const int b5 = lane >> 5;
    const int qsub = wid & 1;
    const int sub = wid >> 1;          // kv half of each staged tile
    const int qbase = blockIdx.x * 64;
    const int bh = blockIdx.y;

    const half_t* Qp = Qh + (size_t)bh * NN * HD;
    const half_t* Kp = Kh + (size_t)bh * NN * HD;
    const half_t* Vp = Vth + (size_t)bh * HD * NN;
    half_t* AOp = AOh + (size_t)bh * NN * HD;

    // ---- preload K/V tile 0 into regs ----
    const int kr = tid >> 2;               // K row 0..63
    const int kcb = (tid & 3) * 48;        // K col byte
    const int vd = tid >> 1;               // V row 0..95 (tid<192)
    const int vcb = (tid & 1) * 64;        // V col byte
    half8 kv0, kv1, kv2, vv0, vv1, vv2, vv3;
    {
        const half_t* ksrc = Kp + (size_t)kr * HD + kcb / 2;
        kv0 = *(const half8*)(ksrc);
        kv1 = *(const half8*)(ksrc + 8);
        kv2 = *(const half8*)(ksrc + 16);
        if (tid < 192) {
            const half_t* vsrc = Vp + (size_t)vd * NN + vcb / 2;
            vv0 = *(const half8*)(vsrc);      vv1 = *(const half8*)(vsrc + 8);
            vv2 = *(const half8*)(vsrc + 16); vv3 = *(const half8*)(vsrc + 24);
        }
    }

    // ---- stage Q [64][96] swizzled, read frags, release LDS ----
    {
        const int r = tid >> 2;
        const int cb = (tid & 3) * 48;
        const half_t* src = Qp + (size_t)(qbase + r) * HD + cb / 2;
        #pragma unroll
        for (int c = 0; c < 3; ++c) {
            half8 q = *(const half8*)(src + c * 8);
            *(half8*)(smem + ((r * 192 + cb + c * 16) ^ ((r & 7) << 4))) = q;
        }
    }
    __syncthreads();
    half8 qf[6];
    {
        const int r = qsub * 32 + l31;
        #pragma unroll
        for (int kg = 0; kg < 6; ++kg)
            qf[kg] = *(const half8*)(smem + ((r * 192 + kg * 32 + 16 * b5) ^ ((r & 7) << 4)));
    }
    __syncthreads();

    // ---- state ----
    f32x16 acc[3];
    const f32x16 z16 = {0.f,0.f,0.f,0.f,0.f,0.f,0.f,0.f,0.f,0.f,0.f,0.f,0.f,0.f,0.f,0.f};
    acc[0] = z16; acc[1] = z16; acc[2] = z16;
    float mreg = -1e30f, lreg = 0.f;

    const int kvrow = sub * 32 + l31;      // this wave's kv row within a tile

    for (int kt = 0; kt < NN / 64; ++kt) {
        // write staged K/V tile (swizzled)
        *(half8*)(smem + ((kr * 192 + kcb +  0) ^ ((kr & 7) << 4))) = kv0;
        *(half8*)(smem + ((kr * 192 + kcb + 16) ^ ((kr & 7) << 4))) = kv1;
        *(half8*)(smem + ((kr * 192 + kcb + 32) ^ ((kr & 7) << 4))) = kv2;
        if (tid < 192) {
            char* vb = smem + 12288;
            *(half8*)(vb + ((vd * 128 + vcb +  0) ^ ((vd & 7) << 4))) = vv0;
            *(half8*)(vb + ((vd * 128 + vcb + 16) ^ ((vd & 7) << 4))) = vv1;
            *(half8*)(vb + ((vd * 128 + vcb + 32) ^ ((vd & 7) << 4))) = vv2;
            *(half8*)(vb + ((vd * 128 + vcb + 48) ^ ((vd & 7) << 4))) = vv3;
        }
        __syncthreads();

        // prefetch next tile
        if (kt + 1 < NN / 64) {
            const int kb = (kt + 1) * 64;
            const half_t* ksrc = Kp + (size_t)(kb + kr) * HD + kcb / 2;
            kv0 = *(const half8*)(ksrc);
            kv1 = *(const half8*)(ksrc + 8);
            kv2 = *(const half8*)(ksrc + 16);
            if (tid < 192) {
                const half_t* vsrc = Vp + (size_t)vd * NN + kb + vcb / 2;
                vv0 = *(const half8*)(vsrc);      vv1 = *(const half8*)(vsrc + 8);
                vv2 = *(const half8*)(vsrc + 16); vv3 = *(const half8*)(vsrc + 24);
            }
        }

        // S^T[kv][q] over this wave's 32-kv subtile
        f32x16 st = z16;
        #pragma unroll
        for (int kg = 0; kg < 6; ++kg) {
            half8 kf = *(const half8*)(smem +
                ((kvrow * 192 + kg * 32 + 16 * b5) ^ ((kvrow & 7) << 4)));
            st = mfma32(kf, qf[kg], st);
        }

        // row max over lane's 16 kv + partner's 16
        float tm = st[0];
        #pragma unroll
        for (int i = 1; i < 16; ++i) tm = fmaxf(tm, st[i]);
        tm = fmaxf(tm, __shfl_xor(tm, 32));

        // defer-max
        if (!__all(tm <= mreg + 8.0f)) {
            const float mn = fmaxf(mreg, tm);
            const float sc = exp2f(mreg - mn);
            lreg *= sc;
            #pragma unroll
            for (int db = 0; db < 3; ++db)
                #pragma unroll
                for (int i = 0; i < 16; ++i) acc[db][i] *= sc;
            mreg = mn;
        }

        // P = exp2(S^T - m), row sum
        float rs = 0.f;
        #pragma unroll
        for (int i = 0; i < 16; ++i) {
            const float p = exp2f(st[i] - mreg);
            st[i] = p;
            rs += p;
        }
        rs += __shfl_xor(rs, 32);
        lreg += rs;

        // pack P to f16
        unsigned pk[4][2];
        #pragma unroll
        for (int rr = 0; rr < 4; ++rr) {
            pk[rr][0] = pkrtz(st[rr*4+0], st[rr*4+1]);
            pk[rr][1] = pkrtz(st[rr*4+2], st[rr*4+3]);
        }

        // P^T B-frags via b5-partner exchange; O^T accumulate
        #pragma unroll
        for (int ks = 0; ks < 2; ++ks) {
            const unsigned z0 = b5 ? pk[2*ks][0] : pk[2*ks+1][0];
            const unsigned z1 = b5 ? pk[2*ks][1] : pk[2*ks+1][1];
            const unsigned x0 = sx32(z0);
            const unsigned x1 = sx32(z1);
            union { unsigned u[4]; half8 h; } afu;
            afu.u[0] = b5 ? x0 : pk[2*ks][0];
            afu.u[1] = b5 ? x1 : pk[2*ks][1];
            afu.u[2] = b5 ? pk[2*ks+1][0] : x0;
            afu.u[3] = b5 ? pk[2*ks+1][1] : x1;
            const half8 af = afu.h;
            #pragma unroll
            for (int db = 0; db < 3; ++db) {
                const int d = db * 32 + l31;
                half8 vf = *(const half8*)(smem + 12288 +
                    ((d * 128 + sub * 64 + ks * 32 + 16 * b5) ^ ((d & 7) << 4)));
                acc[db] = mfma32(vf, af, acc[db]);
            }
        }
        __syncthreads();
    }

    // ---- combine wave pairs (0,2) and (1,3) ----
    float* fb = (float*)smem;
    fb[tid] = mreg;
    fb[256 + tid] = lreg;
    __syncthreads();
    const float mp = fb[tid ^ 128];
    const float lp = fb[256 + (tid ^ 128)];
    const float mc = fmaxf(mreg, mp);
    const float sc = exp2f(mreg - mc);
    const float lc = lreg * sc + lp * exp2f(mp - mc);
    __syncthreads();
    if (wid >= 2) {
        float* rec = fb + (qsub * 64 + lane) * 49;
        #pragma unroll
        for (int db = 0; db < 3; ++db)
            #pragma unroll
            for (int i = 0; i < 16; ++i) rec[db*16 + i] = acc[db][i] * sc;
    }
    __syncthreads();
    if (wid < 2) {
        const float* rec = fb + (qsub * 64 + lane) * 49;
        const float isq = 0.10206207261596577f;   // 1/sqrt(96), post-softmax per ref
        const float inv = isq / lc;
        const int q = qbase + qsub * 32 + l31;
        half_t* dst = AOp + (size_t)q * HD;
        #pragma unroll
        for (int db = 0; db < 3; ++db)
            #pragma unroll
            for (int rr = 0; rr < 4; ++rr) {
                const int d0 = db * 32 + rr * 8 + 4 * b5;
                union { half_t h[4]; uint2 u; } t;
                #pragma unroll
                for (int r = 0; r < 4; ++r)
                    t.h[r] = (half_t)((acc[db][rr*4 + r] * sc + rec[db*16 + rr*4 + r]) * inv);
                *(uint2*)&dst[d0] = t.u;
            }
    }
}

// ---------------------------------------------------------------------------
// Output projection: out(fp32) = AO(head-split f16) @ WoT + bo.
// ---------------------------------------------------------------------------
__global__ __launch_bounds__(256) void proj_out_h(
    const half_t* __restrict__ AOh, const half_t* __restrict__ WoT,
    const float* __restrict__ bo, float* __restrict__ out)
{
    __shared__ half_t As[128][56];
    __shared__ half_t Bs[128][56];

    const int tid = threadIdx.x;
    const int lane = tid & 63;
    const int wid = tid >> 6;
    const int lr = lane & 15;
    const int lkg = lane >> 4;
    const int wm = (wid >> 1) * 64;
    const int wn = (wid & 1) * 64;
    const int mbase = blockIdx.x * 128;
    const int nbase = blockIdx.y * 128;

    const int srr = tid >> 2;
    const int skk = (tid & 3) * 8;

    const int arow0 = mbase + srr;
    const int ab0 = arow0 >> 11, an0 = arow0 & (NN - 1);
    const int arow1 = arow0 + 64;
    const int ab1 = arow1 >> 11, an1 = arow1 & (NN - 1);

    f32x4 acc[4][4];
    const f32x4 z4 = {0.f, 0.f, 0.f, 0.f};
    #pragma unroll
    for (int i = 0; i < 4; ++i)
        #pragma unroll
        for (int j = 0; j < 4; ++j) acc[i][j] = z4;

    const half_t* bptr = WoT + (size_t)(nbase + srr) * EMB + skk;

#define ALOAD(b_, n_, k0_) \
    (*(const half8*)&AOh[((size_t)((b_)*HEADS + (k0_)/HD) * NN + (n_)) * HD + ((k0_)%HD) + skk])

    half8 a0 = ALOAD(ab0, an0, 0);
    half8 a1 = ALOAD(ab1, an1, 0);
    half8 b0 = *(const half8*)bptr;
    half8 b1 = *(const half8*)(bptr + 64 * EMB);

    for (int k0 = 0; k0 < EMB; k0 += 32) {
        __syncthreads();
        *(half8*)&As[srr][skk]      = a0;
        *(half8*)&As[srr + 64][skk] = a1;
        *(half8*)&Bs[srr][skk]      = b0;
        *(half8*)&Bs[srr + 64][skk] = b1;
        __syncthreads();
        if (k0 + 32 < EMB) {
            const int kn = k0 + 32;
            a0 = ALOAD(ab0, an0, kn);
            a1 = ALOAD(ab1, an1, kn);
            b0 = *(const half8*)(bptr + kn);
            b1 = *(const half8*)(bptr + kn + 64 * EMB);
        }
        half8 af[4], bf[4];
        #pragma unroll
        for (int mi = 0; mi < 4; ++mi)
            af[mi] = *(const half8*)&As[wm + mi*16 + lr][lkg*8];
        #pragma unroll
        for (int ni = 0; ni < 4; ++ni)
            bf[ni] = *(const half8*)&Bs[wn + ni*16 + lr][lkg*8];
        #pragma unroll
        for (int mi = 0; mi < 4; ++mi)
            #pragma unroll
            for (int ni = 0; ni < 4; ++ni)
                acc[mi][ni] = mfma16(af[mi], bf[ni], acc[mi][ni]);
    }
#undef ALOAD

    #pragma unroll
    for (int ni = 0; ni < 4; ++ni) {
        const int e = nbase + wn + ni*16 + lr;
        const float be = bo[e];
        #pragma unroll
        for (int mi = 0; mi < 4; ++mi) {
            const int row0 = mbase + wm + mi*16 + lkg*4;
            #pragma unroll
            for (int r = 0; r < 4; ++r)
                out[(size_t)(row0 + r) * EMB + e] = acc[mi][ni][r] + be;
        }
    }
}

// ---------------------------------------------------------------------------
extern "C" void kernel_launch(void* const* d_in, const int* in_sizes, int n_in,
                              void* d_out, int out_size, void* d_ws, size_t ws_size,
                              hipStream_t stream)
{
    const float* x  = (const float*)d_in[0];
    const float* Wq = (const float*)d_in[1];
    const float* bq = (const float*)d_in[2];
    const float* Wk = (const float*)d_in[3];
    const float* bk = (const float*)d_in[4];
    const float* Wv = (const float*)d_in[5];
    const float* bv = (const float*)d_in[6];
    const float* Wo = (const float*)d_in[7];
    const float* bo = (const float*)d_in[8];

    const size_t SZ = (size_t)BN * EMB;   // 6,291,456
    const size_t WS = (size_t)EMB * EMB;  //   589,824

    half_t* ws  = (half_t*)d_ws;
    half_t* WqT = ws;
    half_t* WkT = WqT + WS;
    half_t* WvT = WkT + WS;
    half_t* WoT = WvT + WS;
    half_t* Qh  = WoT + WS;
    half_t* Kh  = Qh  + SZ;
    half_t* Vth = Kh  + SZ;
    half_t* AOh = Vth + SZ;

    cvt_transpose_w<<<dim3(EMB/32, EMB/32, 4), 256, 0, stream>>>(
        Wq, Wk, Wv, Wo, WqT, WkT, WvT, WoT);

    proj_qkv_h<<<dim3(BN/128, EMB/128, 3), 256, 0, stream>>>(
        x, WqT, bq, WkT, bk, WvT, bv, Qh, Kh, Vth);

    attn_h<<<dim3(NN/64, BB*HEADS), 256, 0, stream>>>(Qh, Kh, Vth, AOh);

    proj_out_h<<<dim3(BN/128, EMB/128), 256, 0, stream>>>(AOh, WoT, bo, (float*)d_out);
}